// Round 12
// baseline (338.308 us; speedup 1.0000x reference)
//
#include <hip/hip_runtime.h>
#include <hip/hip_bf16.h>

typedef __hip_bfloat16 bf16;
typedef __attribute__((ext_vector_type(8))) short bf16x8;
typedef __attribute__((ext_vector_type(4))) float f32x4;

#define HID 128
#define PD  16
#define BB  4096
#define TT  262144
#define VD  10000
#define VP  4000
#define VA  4000
#define NGD 13000
#define NGP 5200
#define NGA 5200
#define VTOT (VD + VP + VA)      // 18000
#define SLICE_ROWS (VTOT / 8)    // 2250

#define NB_D ((NGD + 31) / 32)   // 407
#define NB_P ((NGP + 31) / 32)   // 163
#define NB_A ((NGA + 31) / 32)   // 163

__device__ __forceinline__ float2 bf2x(unsigned int u) {
    float lo = __uint_as_float(u << 16);
    float hi = __uint_as_float(u & 0xffff0000u);
    return make_float2(lo, hi);
}

union Pack2 { bf16 h[2]; unsigned int u; };
__device__ __forceinline__ unsigned int pk2(float a, float b) {
    Pack2 p; p.h[0] = __float2bfloat16(a); p.h[1] = __float2bfloat16(b); return p.u;
}
__device__ __forceinline__ short bfs(float x) {
    bf16 h = __float2bfloat16(x);
    return *reinterpret_cast<short*>(&h);
}
union FragU { short s[8]; bf16x8 v; uint4 u; };

// ---------------- K0 (merged prologue):
//   [0,48):    prep_b3 — stage1 W fragments
//   [48,81):   seg_bounds + zero s_sum
//   [81,209):  prep_w3 — 3-way bf16 split of W_ntn
//   [209,273): zero le/re (segsum now accumulates atomically)
__global__ __launch_bounds__(256) void prologue(
    const float* __restrict__ Wl_d, const float* __restrict__ Wl_p, const float* __restrict__ Wl_a,
    bf16* __restrict__ B3_d, bf16* __restrict__ B3_p, bf16* __restrict__ B3_a,
    const int* __restrict__ lb, const int* __restrict__ rb,
    int* __restrict__ segL, int* __restrict__ segR, float* __restrict__ s_sum,
    const float* __restrict__ W2,
    bf16* __restrict__ W3h, bf16* __restrict__ W3m, bf16* __restrict__ W3l,
    float* __restrict__ lere)
{
    __shared__ float LW[128][17];
    const int bx = blockIdx.x;
    const int tid = threadIdx.x;
    if (bx < 48) {
        const int sec = bx >> 4, jt = bx & 15;
        const float* Wl = (sec == 0) ? Wl_d : (sec == 1) ? Wl_p : Wl_a;
        bf16* B3 = (sec == 0) ? B3_d : (sec == 1) ? B3_p : B3_a;
        const int q = tid >> 6, lane = tid & 63;
        const int quad = lane >> 4, m = lane & 15;
        const int col = jt * 16 + m;
        const float* src = (col < 128) ? (Wl + col * 256) : (Wl + (col - 128) * 256 + 128);
        unsigned int pk[4];
#pragma unroll
        for (int jp = 0; jp < 4; ++jp) {
            int k0 = q * 32 + quad * 8 + 2 * jp;
            pk[jp] = pk2(src[k0], src[k0 + 1]);
        }
        uint4 val = make_uint4(pk[0], pk[1], pk[2], pk[3]);
        *reinterpret_cast<uint4*>(B3 + ((size_t)(jt * 4 + q) * 64 + lane) * 8) = val;
    } else if (bx < 81) {
        int gid = (bx - 48) * 256 + tid;
        if (gid >= 2 * BB + 8 && gid < 2 * BB + 24) s_sum[gid - (2 * BB + 8)] = 0.f;
        const int* batch;
        int* segp;
        int b;
        if (gid <= BB) { batch = lb; segp = segL; b = gid; }
        else if (gid <= 2 * BB + 1) { batch = rb; segp = segR; b = gid - BB - 1; }
        else return;
        int l = 0, r = TT;
        while (l < r) { int m2 = (l + r) >> 1; if (batch[m2] < b) l = m2 + 1; else r = m2; }
        segp[b] = l;
    } else if (bx < 209) {
        const int t = bx - 81;   // col-tile 0..127
        for (int idx = tid; idx < 2048; idx += 256) {
            int k = idx >> 4, m = idx & 15;
            LW[k][m] = W2[(size_t)k * 2048 + 16 * t + m];
        }
        __syncthreads();
        const int q = tid >> 6, lane = tid & 63;
        const int m = lane & 15, quad = lane >> 4;
        FragU fh, fm, fl;
#pragma unroll
        for (int j = 0; j < 8; ++j) {
            float x = LW[32 * q + quad * 8 + j][m];
            bf16 h = __float2bfloat16(x);
            float r = x - __bfloat162float(h);
            bf16 md = __float2bfloat16(r);
            float r2 = r - __bfloat162float(md);
            fh.s[j] = *reinterpret_cast<short*>(&h);
            fm.s[j] = *reinterpret_cast<short*>(&md);
            fl.s[j] = bfs(r2);
        }
        size_t off = ((size_t)(t * 4 + q) * 64 + lane) * 8;
        *reinterpret_cast<uint4*>(W3h + off) = fh.u;
        *reinterpret_cast<uint4*>(W3m + off) = fm.u;
        *reinterpret_cast<uint4*>(W3l + off) = fl.u;
    } else {
        // zero le+re (contiguous 2*BB*HID floats = 262144 float4)
        float4* p = reinterpret_cast<float4*>(lere);
        int base = (bx - 209) * 256 + tid;  // 0..16383
        float4 z = make_float4(0.f, 0.f, 0.f, 0.f);
#pragma unroll
        for (int i = 0; i < 16; ++i) p[base + i * 16384] = z;
    }
}

// ---------------- K1: U[g, 0..255] via bf16 MFMA
__device__ __forceinline__ void stage1_body(
    unsigned short (*Abf)[136],
    const float* __restrict__ emb, const bf16* __restrict__ B3,
    bf16* __restrict__ U, int NG, int blk)
{
    const int tid  = threadIdx.x;
    const int row0 = blk * 32;
    {
        const int r = tid >> 3, seg = tid & 7;
        const int g = row0 + r;
        float v[16];
        if (g < NG) {
            const float4* src = reinterpret_cast<const float4*>(emb + (size_t)g * HID + seg * 16);
#pragma unroll
            for (int i = 0; i < 4; ++i) {
                float4 f = src[i];
                v[4 * i] = f.x; v[4 * i + 1] = f.y; v[4 * i + 2] = f.z; v[4 * i + 3] = f.w;
            }
        } else {
#pragma unroll
            for (int i = 0; i < 16; ++i) v[i] = 0.f;
        }
        unsigned int pk[8];
#pragma unroll
        for (int i = 0; i < 8; ++i) pk[i] = pk2(v[2 * i], v[2 * i + 1]);
        uint4* dst = reinterpret_cast<uint4*>(&Abf[r][seg * 16]);
        dst[0] = make_uint4(pk[0], pk[1], pk[2], pk[3]);
        dst[1] = make_uint4(pk[4], pk[5], pk[6], pk[7]);
    }
    __syncthreads();

    const int lane   = tid & 63;
    const int w      = tid >> 6;
    const int gtile  = w & 1;
    const int jstrip = w >> 1;
    const int lrow   = gtile * 16 + (lane & 15);
    const int koff   = (lane >> 4) * 8;
    const bf16x8* B3f = reinterpret_cast<const bf16x8*>(B3);

    f32x4 acc[8];
#pragma unroll
    for (int t = 0; t < 8; ++t) acc[t] = (f32x4){0.f, 0.f, 0.f, 0.f};

#pragma unroll
    for (int q = 0; q < 4; ++q) {
        bf16x8 ef = *reinterpret_cast<const bf16x8*>(&Abf[lrow][q * 32 + koff]);
#pragma unroll
        for (int t = 0; t < 8; ++t) {
            int jt = jstrip * 8 + t;
            bf16x8 wf = B3f[(jt * 4 + q) * 64 + lane];
            acc[t] = __builtin_amdgcn_mfma_f32_16x16x32_bf16(wf, ef, acc[t], 0, 0, 0);
        }
    }

    const int g = row0 + gtile * 16 + (lane & 15);
    if (g < NG) {
        const int quad = lane >> 4;
        bf16* Ur = U + (size_t)g * 256;
#pragma unroll
        for (int t = 0; t < 8; ++t) {
            int j0 = (jstrip * 8 + t) * 16 + quad * 4;
            uint2 st = make_uint2(pk2(acc[t].x, acc[t].y), pk2(acc[t].z, acc[t].w));
            *reinterpret_cast<uint2*>(Ur + j0) = st;
        }
    }
}

__global__ __launch_bounds__(256) void stage1_mfma(
    const float* __restrict__ emb_d, const bf16* __restrict__ B3_d, bf16* __restrict__ U_d,
    const float* __restrict__ emb_p, const bf16* __restrict__ B3_p, bf16* __restrict__ U_p,
    const float* __restrict__ emb_a, const bf16* __restrict__ B3_a, bf16* __restrict__ U_a)
{
    __shared__ unsigned short Abf[32][136];
    int bx = blockIdx.x;
    if (bx < NB_D)             stage1_body(Abf, emb_d, B3_d, U_d, NGD, bx);
    else if (bx < NB_D + NB_P) stage1_body(Abf, emb_p, B3_p, U_p, NGP, bx - NB_D);
    else                       stage1_body(Abf, emb_a, B3_a, U_a, NGA, bx - NB_D - NB_P);
}

// ---------------- K2: aw + softmax + global s_sum  (2 vertices per iteration)
template <int L>
__device__ __forceinline__ void aw_body(
    float* sacc,
    const bf16* __restrict__ U, const int* __restrict__ anc, const int* __restrict__ leaf,
    const float* __restrict__ bl, const float* __restrict__ ap,
    float* __restrict__ s_out, int V, int blk, int nblk)
{
    const int tid  = threadIdx.x;
    const int lane = tid & 63;
    const int wid  = blk * 4 + (tid >> 6);
    const int nw   = nblk * 4;
    const float2 blv = *reinterpret_cast<const float2*>(bl + 2 * lane);
    const float2 apv = *reinterpret_cast<const float2*>(ap + 2 * lane);
    const unsigned int* Uw = reinterpret_cast<const unsigned int*>(U);
    float wacc[L];
#pragma unroll
    for (int l = 0; l < L; ++l) wacc[l] = 0.f;

    for (int vp = wid; vp < V / 2; vp += nw) {
        const int v0 = 2 * vp;
        int a0[L], f0[L], a1[L], f1[L];
        if (L == 4) {
            int4 ia = *reinterpret_cast<const int4*>(anc  + (size_t)v0 * 4);
            int4 ib = *reinterpret_cast<const int4*>(anc  + (size_t)v0 * 4 + 4);
            int4 fa = *reinterpret_cast<const int4*>(leaf + (size_t)v0 * 4);
            int4 fb = *reinterpret_cast<const int4*>(leaf + (size_t)v0 * 4 + 4);
            a0[0] = ia.x; a0[1] = ia.y; a0[2] = ia.z; a0[3] = ia.w;
            a1[0] = ib.x; a1[1] = ib.y; a1[2] = ib.z; a1[3] = ib.w;
            f0[0] = fa.x; f0[1] = fa.y; f0[2] = fa.z; f0[3] = fa.w;
            f1[0] = fb.x; f1[1] = fb.y; f1[2] = fb.z; f1[3] = fb.w;
        } else {
#pragma unroll
            for (int l = 0; l < L; ++l) {
                a0[l] = anc[(size_t)v0 * L + l];
                a1[l] = anc[(size_t)(v0 + 1) * L + l];
                f0[l] = leaf[(size_t)v0 * L + l];
                f1[l] = leaf[(size_t)(v0 + 1) * L + l];
            }
        }
        unsigned int ua0[L], ul0[L], ua1[L], ul1[L];
#pragma unroll
        for (int l = 0; l < L; ++l) {
            ua0[l] = Uw[(size_t)a0[l] * 128 + lane];
            ul0[l] = Uw[(size_t)f0[l] * 128 + 64 + lane];
            ua1[l] = Uw[(size_t)a1[l] * 128 + lane];
            ul1[l] = Uw[(size_t)f1[l] * 128 + 64 + lane];
        }
        float aw0[L], aw1[L];
#pragma unroll
        for (int l = 0; l < L; ++l) {
            float2 x0 = bf2x(ua0[l]), y0 = bf2x(ul0[l]);
            float2 x1 = bf2x(ua1[l]), y1 = bf2x(ul1[l]);
            float p0 = tanhf(x0.x + y0.x + blv.x) * apv.x + tanhf(x0.y + y0.y + blv.y) * apv.y;
            float p1 = tanhf(x1.x + y1.x + blv.x) * apv.x + tanhf(x1.y + y1.y + blv.y) * apv.y;
#pragma unroll
            for (int off = 32; off; off >>= 1) {
                p0 += __shfl_xor(p0, off, 64);
                p1 += __shfl_xor(p1, off, 64);
            }
            aw0[l] = p0; aw1[l] = p1;
        }
        float m0 = aw0[0], m1 = aw1[0];
#pragma unroll
        for (int l = 1; l < L; ++l) { m0 = fmaxf(m0, aw0[l]); m1 = fmaxf(m1, aw1[l]); }
        float d0 = 0.f, d1 = 0.f, e0[L], e1[L];
#pragma unroll
        for (int l = 0; l < L; ++l) {
            e0[l] = __expf(aw0[l] - m0); d0 += e0[l];
            e1[l] = __expf(aw1[l] - m1); d1 += e1[l];
        }
        float i0 = 1.f / d0, i1 = 1.f / d1;
#pragma unroll
        for (int l = 0; l < L; ++l) wacc[l] += e0[l] * i0 + e1[l] * i1;
    }
    if (lane == 0) {
#pragma unroll
        for (int l = 0; l < L; ++l) atomicAdd(&sacc[l], wacc[l]);
    }
    __syncthreads();
    if (tid < L) atomicAdd(&s_out[tid], sacc[tid]);
}

__global__ __launch_bounds__(256) void aw_all(
    const bf16* __restrict__ U_d, const int* __restrict__ anc_d, const int* __restrict__ leaf_d,
    const float* __restrict__ bl_d, const float* __restrict__ ap_d,
    const bf16* __restrict__ U_p, const int* __restrict__ anc_p, const int* __restrict__ leaf_p,
    const float* __restrict__ bl_p, const float* __restrict__ ap_p,
    const bf16* __restrict__ U_a, const int* __restrict__ anc_a, const int* __restrict__ leaf_a,
    const float* __restrict__ bl_a, const float* __restrict__ ap_a,
    float* __restrict__ s_sum)
{
    __shared__ float sacc[5];
    const int tid = threadIdx.x;
    if (tid < 5) sacc[tid] = 0.f;
    __syncthreads();
    int bx = blockIdx.x;
    if (bx < 512)      aw_body<4>(sacc, U_d, anc_d, leaf_d, bl_d, ap_d, s_sum + 0, VD, bx, 512);
    else if (bx < 768) aw_body<4>(sacc, U_p, anc_p, leaf_p, bl_p, ap_p, s_sum + 4, VP, bx - 512, 256);
    else               aw_body<5>(sacc, U_a, anc_a, leaf_a, bl_a, ap_a, s_sum + 8, VA, bx - 768, 256);
}

// ---------------- K3: all_emb (float4 gathers, 2 vertices per iteration)
template <int L>
__device__ __forceinline__ void allemb_body(
    const float* __restrict__ emb, const int* __restrict__ anc,
    const float* __restrict__ s, float* __restrict__ out, int V, int blk, int nblk)
{
    const int tid   = threadIdx.x;
    const int lane4 = tid & 31;
    const int vslot = tid >> 5;
    const float4* emb4 = reinterpret_cast<const float4*>(emb);
    float4* out4 = reinterpret_cast<float4*>(out);
    float sv[L];
#pragma unroll
    for (int l = 0; l < L; ++l) sv[l] = s[l];
    for (int vp = blk * 8 + vslot; vp < V / 2; vp += nblk * 8) {
        const int v0 = 2 * vp;
        int a0[L], a1[L];
        if (L == 4) {
            int4 ia = *reinterpret_cast<const int4*>(anc + (size_t)v0 * 4);
            int4 ib = *reinterpret_cast<const int4*>(anc + (size_t)v0 * 4 + 4);
            a0[0] = ia.x; a0[1] = ia.y; a0[2] = ia.z; a0[3] = ia.w;
            a1[0] = ib.x; a1[1] = ib.y; a1[2] = ib.z; a1[3] = ib.w;
        } else {
#pragma unroll
            for (int l = 0; l < L; ++l) {
                a0[l] = anc[(size_t)v0 * L + l];
                a1[l] = anc[(size_t)(v0 + 1) * L + l];
            }
        }
        float4 e0[L], e1[L];
#pragma unroll
        for (int l = 0; l < L; ++l) {
            e0[l] = emb4[(size_t)a0[l] * 32 + lane4];
            e1[l] = emb4[(size_t)a1[l] * 32 + lane4];
        }
        float4 r0 = make_float4(0.f, 0.f, 0.f, 0.f);
        float4 r1 = make_float4(0.f, 0.f, 0.f, 0.f);
#pragma unroll
        for (int l = 0; l < L; ++l) {
            r0.x += sv[l] * e0[l].x; r0.y += sv[l] * e0[l].y;
            r0.z += sv[l] * e0[l].z; r0.w += sv[l] * e0[l].w;
            r1.x += sv[l] * e1[l].x; r1.y += sv[l] * e1[l].y;
            r1.z += sv[l] * e1[l].z; r1.w += sv[l] * e1[l].w;
        }
        out4[(size_t)v0 * 32 + lane4]       = r0;
        out4[(size_t)(v0 + 1) * 32 + lane4] = r1;
    }
}

__global__ __launch_bounds__(256) void allemb_all(
    const float* __restrict__ emb_d, const int* __restrict__ anc_d,
    const float* __restrict__ emb_p, const int* __restrict__ anc_p,
    const float* __restrict__ emb_a, const int* __restrict__ anc_a,
    const float* __restrict__ s_sum, float* __restrict__ all_emb)
{
    int bx = blockIdx.x;
    if (bx < 512)
        allemb_body<4>(emb_d, anc_d, s_sum + 0, all_emb, VD, bx, 512);
    else if (bx < 768)
        allemb_body<4>(emb_p, anc_p, s_sum + 4, all_emb + (size_t)VD * HID, VP, bx - 512, 256);
    else
        allemb_body<5>(emb_a, anc_a, s_sum + 8, all_emb + (size_t)(VD + VP) * HID, VA, bx - 768, 256);
}

// ---------------- K4: XCD-sharded segment sum.
// grid = BB*8; b = bid>>3, slice s = bid&7 (round-robin -> same XCD per slice).
// Each block gathers only rows v in [s*2250,(s+1)*2250) — 1.15 MB, L2-resident.
// Accumulate into pre-zeroed le/re via f32 atomics (<=8-way per address).
__global__ __launch_bounds__(128) void segsum_xcd(
    const float* __restrict__ all_emb,
    const int* __restrict__ lx, const int* __restrict__ segL, float* __restrict__ le,
    const int* __restrict__ rx, const int* __restrict__ segR, float* __restrict__ re)
{
    __shared__ float4 red[4][32];
    const int tid   = threadIdx.x;
    const int b     = blockIdx.x >> 3;
    const int s     = blockIdx.x & 7;
    const int v0    = s * SLICE_ROWS;
    const int v1    = v0 + SLICE_ROWS;
    const int lane4 = tid & 31;
    const int slot  = tid >> 5;     // 0..3
    const float4* AE4 = reinterpret_cast<const float4*>(all_emb);

#pragma unroll
    for (int side = 0; side < 2; ++side) {
        const int* x   = side ? rx : lx;
        const int* seg = side ? segR : segL;
        float* out     = side ? re : le;
        const int lo = seg[b], hi = seg[b + 1];
        float4 acc = make_float4(0.f, 0.f, 0.f, 0.f);
        for (int t = lo + slot; t < hi; t += 4) {
            int idx = x[t];
            if (idx >= v0 && idx < v1) {
                float4 v = AE4[(size_t)idx * 32 + lane4];
                acc.x += v.x; acc.y += v.y; acc.z += v.z; acc.w += v.w;
            }
        }
        red[slot][lane4] = acc;
        __syncthreads();
        if (slot == 0) {
            float4 r1 = red[1][lane4], r2 = red[2][lane4], r3 = red[3][lane4];
            acc.x += r1.x + r2.x + r3.x;
            acc.y += r1.y + r2.y + r3.y;
            acc.z += r1.z + r2.z + r3.z;
            acc.w += r1.w + r2.w + r3.w;
            float* dst = out + (size_t)b * HID + lane4 * 4;
            atomicAdd(dst + 0, acc.x);
            atomicAdd(dst + 1, acc.y);
            atomicAdd(dst + 2, acc.z);
            atomicAdd(dst + 3, acc.w);
        }
        __syncthreads();
    }
}

// ---------------- K5a: NTN bilinear via split-bf16 MFMA (6 cross-products ≈ f32).
__global__ __launch_bounds__(256) void ntn_mfma(
    const float* __restrict__ le, const float* __restrict__ re,
    const bf16* __restrict__ W3h, const bf16* __restrict__ W3m, const bf16* __restrict__ W3l,
    float* __restrict__ part)
{
    __shared__ float Rlds[64][17];
    const int tid  = threadIdx.x;
    const int bg   = blockIdx.x;     // 0..63
    const int ch   = blockIdx.y;     // 0..7
    const int w    = tid >> 6;
    const int lane = tid & 63;
    const int m    = lane & 15;
    const int quad = lane >> 4;
    const int rb   = bg * 64 + w * 16 + m;

    for (int idx = tid; idx < 1024; idx += 256) {
        int row = idx >> 4, jl = idx & 15;
        Rlds[row][jl] = re[(size_t)(bg * 64 + row) * HID + ch * 16 + jl];
    }

    bf16x8 lh[4], lm[4], ll[4];
    {
        const float* lp = le + (size_t)rb * HID + quad * 8;
#pragma unroll
        for (int q = 0; q < 4; ++q) {
            float4 f0 = *reinterpret_cast<const float4*>(lp + 32 * q);
            float4 f1 = *reinterpret_cast<const float4*>(lp + 32 * q + 4);
            float x[8] = {f0.x, f0.y, f0.z, f0.w, f1.x, f1.y, f1.z, f1.w};
            FragU fh, fm, fl;
#pragma unroll
            for (int j = 0; j < 8; ++j) {
                bf16 h = __float2bfloat16(x[j]);
                float r = x[j] - __bfloat162float(h);
                bf16 md = __float2bfloat16(r);
                float r2 = r - __bfloat162float(md);
                fh.s[j] = *reinterpret_cast<short*>(&h);
                fm.s[j] = *reinterpret_cast<short*>(&md);
                fl.s[j] = bfs(r2);
            }
            lh[q] = fh.v; lm[q] = fm.v; ll[q] = fl.v;
        }
    }
    __syncthreads();

    const bf16x8* Whf = reinterpret_cast<const bf16x8*>(W3h);
    const bf16x8* Wmf = reinterpret_cast<const bf16x8*>(W3m);
    const bf16x8* Wlf = reinterpret_cast<const bf16x8*>(W3l);

    float blin[4] = {0.f, 0.f, 0.f, 0.f};
#pragma unroll 2
    for (int tl = 0; tl < 16; ++tl) {
        const int t = ch * 16 + tl;
        f32x4 acc = (f32x4){0.f, 0.f, 0.f, 0.f};
#pragma unroll
        for (int q = 0; q < 4; ++q) {
            const int fi = (t * 4 + q) * 64 + lane;
            bf16x8 wh = Whf[fi], wm = Wmf[fi], wl = Wlf[fi];
            acc = __builtin_amdgcn_mfma_f32_16x16x32_bf16(wh, lh[q], acc, 0, 0, 0);
            acc = __builtin_amdgcn_mfma_f32_16x16x32_bf16(wh, lm[q], acc, 0, 0, 0);
            acc = __builtin_amdgcn_mfma_f32_16x16x32_bf16(wm, lh[q], acc, 0, 0, 0);
            acc = __builtin_amdgcn_mfma_f32_16x16x32_bf16(wh, ll[q], acc, 0, 0, 0);
            acc = __builtin_amdgcn_mfma_f32_16x16x32_bf16(wl, lh[q], acc, 0, 0, 0);
            acc = __builtin_amdgcn_mfma_f32_16x16x32_bf16(wm, lm[q], acc, 0, 0, 0);
        }
        float rt = Rlds[w * 16 + m][tl];
        blin[0] += acc.x * rt;
        blin[1] += acc.y * rt;
        blin[2] += acc.z * rt;
        blin[3] += acc.w * rt;
    }

    size_t base = ((size_t)ch * BB + rb) * PD + quad * 4;
    *reinterpret_cast<float4*>(&part[base]) = make_float4(blin[0], blin[1], blin[2], blin[3]);
}

// ---------------- K5b: sum partials + block term + tanh + fc + sigmoid
__global__ __launch_bounds__(256) void ntn_epi(
    const float* __restrict__ part, const float* __restrict__ le, const float* __restrict__ re,
    const float* __restrict__ Vntn, const float* __restrict__ bntn,
    const float* __restrict__ wfc, const float* __restrict__ bfc,
    float* __restrict__ out)
{
    __shared__ float Vlds[16 * 257];
    __shared__ float LE[16 * 128];
    __shared__ float RE[16 * 128];
    const int tid = threadIdx.x;
    const int b0  = blockIdx.x * 16;
    for (int i = tid; i < 4096; i += 256) Vlds[(i >> 8) * 257 + (i & 255)] = Vntn[i];
    for (int i = tid; i < 2048; i += 256) {
        LE[i] = le[(size_t)b0 * HID + i];
        RE[i] = re[(size_t)b0 * HID + i];
    }
    __syncthreads();
    const int bl = tid >> 4, p = tid & 15;
    const int b  = b0 + bl;
    float bil = 0.f;
#pragma unroll
    for (int by = 0; by < 8; ++by) bil += part[((size_t)by * BB + b) * PD + p];
    float s = bil + bntn[p];
    const float* Vp   = &Vlds[p * 257];
    const float* lrow = &LE[bl * 128];
    const float* rrow = &RE[bl * 128];
#pragma unroll 8
    for (int c = 0; c < 128; ++c) s += lrow[c] * Vp[c] + rrow[c] * Vp[128 + c];
    float x = tanhf(s) * wfc[p];
    x += __shfl_xor(x, 1, 64);
    x += __shfl_xor(x, 2, 64);
    x += __shfl_xor(x, 4, 64);
    x += __shfl_xor(x, 8, 64);
    if (p == 0) out[b] = 1.f / (1.f + __expf(-(x + bfc[0])));
}

extern "C" void kernel_launch(void* const* d_in, const int* in_sizes, int n_in,
                              void* d_out, int out_size, void* d_ws, size_t ws_size,
                              hipStream_t stream)
{
    const int* left_x      = (const int*)d_in[0];
    const int* right_x     = (const int*)d_in[2];
    const int* left_batch  = (const int*)d_in[4];
    const int* right_batch = (const int*)d_in[5];
    const int* anc_d  = (const int*)d_in[8];
    const int* leaf_d = (const int*)d_in[9];
    const int* anc_p  = (const int*)d_in[10];
    const int* leaf_p = (const int*)d_in[11];
    const int* anc_a  = (const int*)d_in[12];
    const int* leaf_a = (const int*)d_in[13];
    const float* emb_d = (const float*)d_in[14];
    const float* emb_p = (const float*)d_in[15];
    const float* emb_a = (const float*)d_in[16];
    const float* Wl_d = (const float*)d_in[17];
    const float* bl_d = (const float*)d_in[18];
    const float* ap_d = (const float*)d_in[19];
    const float* Wl_p = (const float*)d_in[20];
    const float* bl_p = (const float*)d_in[21];
    const float* ap_p = (const float*)d_in[22];
    const float* Wl_a = (const float*)d_in[23];
    const float* bl_a = (const float*)d_in[24];
    const float* ap_a = (const float*)d_in[25];
    const float* W_ntn = (const float*)d_in[26];
    const float* V_ntn = (const float*)d_in[27];
    const float* b_ntn = (const float*)d_in[28];
    const float* w_fc  = (const float*)d_in[29];
    const float* b_fc  = (const float*)d_in[30];
    float* out = (float*)d_out;

    float* ws = (float*)d_ws;
    float* s_sum   = ws;                                    // 64 floats (16 used)
    float* le      = ws + 64;                               // 4096*128
    float* re      = le + (size_t)BB * HID;                 // 4096*128 (contiguous with le)
    float* all_emb = re + (size_t)BB * HID;                 // 18000*128
    float* part    = all_emb + (size_t)VTOT * HID;          // 8*4096*16
    int*   segL    = (int*)(part + (size_t)8 * BB * PD);    // 4100
    int*   segR    = segL + 4100;                           // 4100
    bf16*  U       = (bf16*)(segR + 4100);                  // 23400*256 bf16
    bf16*  U_d = U;
    bf16*  U_p = U_d + (size_t)NGD * 256;
    bf16*  U_a = U_p + (size_t)NGP * 256;
    bf16*  B3_d = U_a + (size_t)NGA * 256;                  // 3 * 32768 bf16
    bf16*  B3_p = B3_d + 32768;
    bf16*  B3_a = B3_p + 32768;
    bf16*  W3h  = B3_a + 32768;                             // 3 * 262144 bf16
    bf16*  W3m  = W3h + 262144;
    bf16*  W3l  = W3m + 262144;

    prologue<<<273, 256, 0, stream>>>(
        Wl_d, Wl_p, Wl_a, B3_d, B3_p, B3_a,
        left_batch, right_batch, segL, segR, s_sum,
        W_ntn, W3h, W3m, W3l, le);

    stage1_mfma<<<NB_D + NB_P + NB_A, 256, 0, stream>>>(
        emb_d, B3_d, U_d, emb_p, B3_p, U_p, emb_a, B3_a, U_a);

    aw_all<<<1024, 256, 0, stream>>>(
        U_d, anc_d, leaf_d, bl_d, ap_d,
        U_p, anc_p, leaf_p, bl_p, ap_p,
        U_a, anc_a, leaf_a, bl_a, ap_a, s_sum);

    allemb_all<<<1024, 256, 0, stream>>>(
        emb_d, anc_d, emb_p, anc_p, emb_a, anc_a, s_sum, all_emb);

    segsum_xcd<<<BB * 8, 128, 0, stream>>>(
        all_emb, left_x, segL, le, right_x, segR, re);

    ntn_mfma<<<dim3(64, 8), 256, 0, stream>>>(le, re, W3h, W3m, W3l, part);

    ntn_epi<<<BB / 16, 256, 0, stream>>>(part, le, re, V_ntn, b_ntn, w_fc, b_fc, out);
}

// Round 13
// 222.675 us; speedup vs baseline: 1.5193x; 1.5193x over previous
//
#include <hip/hip_runtime.h>
#include <hip/hip_bf16.h>

typedef __hip_bfloat16 bf16;
typedef __attribute__((ext_vector_type(8))) short bf16x8;
typedef __attribute__((ext_vector_type(4))) float f32x4;

#define HID 128
#define PD  16
#define BB  4096
#define TT  262144
#define VD  10000
#define VP  4000
#define VA  4000
#define NGD 13000
#define NGP 5200
#define NGA 5200

#define NB_D ((NGD + 31) / 32)   // 407
#define NB_P ((NGP + 31) / 32)   // 163
#define NB_A ((NGA + 31) / 32)   // 163

__device__ __forceinline__ float2 bf2x(unsigned int u) {
    float lo = __uint_as_float(u << 16);
    float hi = __uint_as_float(u & 0xffff0000u);
    return make_float2(lo, hi);
}

union Pack2 { bf16 h[2]; unsigned int u; };
__device__ __forceinline__ unsigned int pk2(float a, float b) {
    Pack2 p; p.h[0] = __float2bfloat16(a); p.h[1] = __float2bfloat16(b); return p.u;
}
__device__ __forceinline__ short bfs(float x) {
    bf16 h = __float2bfloat16(x);
    return *reinterpret_cast<short*>(&h);
}
union FragU { short s[8]; bf16x8 v; uint4 u; };

// ---------------- K0 (merged prologue):
//   blocks [0,48):   prep_b3 — stage1's W fragments (bf16, fragment-major)
//   blocks [48,81):  seg_bounds + zero s_sum
//   blocks [81,209): prep_w3 — 3-way bf16 split of W_ntn, fragment-major (A-operand)
__global__ __launch_bounds__(256) void prologue(
    const float* __restrict__ Wl_d, const float* __restrict__ Wl_p, const float* __restrict__ Wl_a,
    bf16* __restrict__ B3_d, bf16* __restrict__ B3_p, bf16* __restrict__ B3_a,
    const int* __restrict__ lb, const int* __restrict__ rb,
    int* __restrict__ segL, int* __restrict__ segR, float* __restrict__ s_sum,
    const float* __restrict__ W2,
    bf16* __restrict__ W3h, bf16* __restrict__ W3m, bf16* __restrict__ W3l)
{
    __shared__ float LW[128][17];
    const int bx = blockIdx.x;
    const int tid = threadIdx.x;
    if (bx < 48) {
        const int sec = bx >> 4, jt = bx & 15;
        const float* Wl = (sec == 0) ? Wl_d : (sec == 1) ? Wl_p : Wl_a;
        bf16* B3 = (sec == 0) ? B3_d : (sec == 1) ? B3_p : B3_a;
        const int q = tid >> 6, lane = tid & 63;
        const int quad = lane >> 4, m = lane & 15;
        const int col = jt * 16 + m;
        const float* src = (col < 128) ? (Wl + col * 256) : (Wl + (col - 128) * 256 + 128);
        unsigned int pk[4];
#pragma unroll
        for (int jp = 0; jp < 4; ++jp) {
            int k0 = q * 32 + quad * 8 + 2 * jp;
            pk[jp] = pk2(src[k0], src[k0 + 1]);
        }
        uint4 val = make_uint4(pk[0], pk[1], pk[2], pk[3]);
        *reinterpret_cast<uint4*>(B3 + ((size_t)(jt * 4 + q) * 64 + lane) * 8) = val;
    } else if (bx < 81) {
        int gid = (bx - 48) * 256 + tid;
        if (gid >= 2 * BB + 8 && gid < 2 * BB + 24) s_sum[gid - (2 * BB + 8)] = 0.f;
        const int* batch;
        int* segp;
        int b;
        if (gid <= BB) { batch = lb; segp = segL; b = gid; }
        else if (gid <= 2 * BB + 1) { batch = rb; segp = segR; b = gid - BB - 1; }
        else return;
        int l = 0, r = TT;
        while (l < r) { int m2 = (l + r) >> 1; if (batch[m2] < b) l = m2 + 1; else r = m2; }
        segp[b] = l;
    } else {
        const int t = bx - 81;   // col-tile 0..127 (16 cols each)
        for (int idx = tid; idx < 2048; idx += 256) {
            int k = idx >> 4, m = idx & 15;
            LW[k][m] = W2[(size_t)k * 2048 + 16 * t + m];
        }
        __syncthreads();
        const int q = tid >> 6, lane = tid & 63;
        const int m = lane & 15, quad = lane >> 4;
        FragU fh, fm, fl;
#pragma unroll
        for (int j = 0; j < 8; ++j) {
            float x = LW[32 * q + quad * 8 + j][m];
            bf16 h = __float2bfloat16(x);
            float r = x - __bfloat162float(h);
            bf16 md = __float2bfloat16(r);
            float r2 = r - __bfloat162float(md);
            fh.s[j] = *reinterpret_cast<short*>(&h);
            fm.s[j] = *reinterpret_cast<short*>(&md);
            fl.s[j] = bfs(r2);
        }
        size_t off = ((size_t)(t * 4 + q) * 64 + lane) * 8;
        *reinterpret_cast<uint4*>(W3h + off) = fh.u;
        *reinterpret_cast<uint4*>(W3m + off) = fm.u;
        *reinterpret_cast<uint4*>(W3l + off) = fl.u;
    }
}

// ---------------- K1: U[g, 0..255] via bf16 MFMA
__device__ __forceinline__ void stage1_body(
    unsigned short (*Abf)[136],
    const float* __restrict__ emb, const bf16* __restrict__ B3,
    bf16* __restrict__ U, int NG, int blk)
{
    const int tid  = threadIdx.x;
    const int row0 = blk * 32;
    {
        const int r = tid >> 3, seg = tid & 7;
        const int g = row0 + r;
        float v[16];
        if (g < NG) {
            const float4* src = reinterpret_cast<const float4*>(emb + (size_t)g * HID + seg * 16);
#pragma unroll
            for (int i = 0; i < 4; ++i) {
                float4 f = src[i];
                v[4 * i] = f.x; v[4 * i + 1] = f.y; v[4 * i + 2] = f.z; v[4 * i + 3] = f.w;
            }
        } else {
#pragma unroll
            for (int i = 0; i < 16; ++i) v[i] = 0.f;
        }
        unsigned int pk[8];
#pragma unroll
        for (int i = 0; i < 8; ++i) pk[i] = pk2(v[2 * i], v[2 * i + 1]);
        uint4* dst = reinterpret_cast<uint4*>(&Abf[r][seg * 16]);
        dst[0] = make_uint4(pk[0], pk[1], pk[2], pk[3]);
        dst[1] = make_uint4(pk[4], pk[5], pk[6], pk[7]);
    }
    __syncthreads();

    const int lane   = tid & 63;
    const int w      = tid >> 6;
    const int gtile  = w & 1;
    const int jstrip = w >> 1;
    const int lrow   = gtile * 16 + (lane & 15);
    const int koff   = (lane >> 4) * 8;
    const bf16x8* B3f = reinterpret_cast<const bf16x8*>(B3);

    f32x4 acc[8];
#pragma unroll
    for (int t = 0; t < 8; ++t) acc[t] = (f32x4){0.f, 0.f, 0.f, 0.f};

#pragma unroll
    for (int q = 0; q < 4; ++q) {
        bf16x8 ef = *reinterpret_cast<const bf16x8*>(&Abf[lrow][q * 32 + koff]);
#pragma unroll
        for (int t = 0; t < 8; ++t) {
            int jt = jstrip * 8 + t;
            bf16x8 wf = B3f[(jt * 4 + q) * 64 + lane];
            acc[t] = __builtin_amdgcn_mfma_f32_16x16x32_bf16(wf, ef, acc[t], 0, 0, 0);
        }
    }

    const int g = row0 + gtile * 16 + (lane & 15);
    if (g < NG) {
        const int quad = lane >> 4;
        bf16* Ur = U + (size_t)g * 256;
#pragma unroll
        for (int t = 0; t < 8; ++t) {
            int j0 = (jstrip * 8 + t) * 16 + quad * 4;
            uint2 st = make_uint2(pk2(acc[t].x, acc[t].y), pk2(acc[t].z, acc[t].w));
            *reinterpret_cast<uint2*>(Ur + j0) = st;
        }
    }
}

__global__ __launch_bounds__(256) void stage1_mfma(
    const float* __restrict__ emb_d, const bf16* __restrict__ B3_d, bf16* __restrict__ U_d,
    const float* __restrict__ emb_p, const bf16* __restrict__ B3_p, bf16* __restrict__ U_p,
    const float* __restrict__ emb_a, const bf16* __restrict__ B3_a, bf16* __restrict__ U_a)
{
    __shared__ unsigned short Abf[32][136];
    int bx = blockIdx.x;
    if (bx < NB_D)             stage1_body(Abf, emb_d, B3_d, U_d, NGD, bx);
    else if (bx < NB_D + NB_P) stage1_body(Abf, emb_p, B3_p, U_p, NGP, bx - NB_D);
    else                       stage1_body(Abf, emb_a, B3_a, U_a, NGA, bx - NB_D - NB_P);
}

// ---------------- K2: aw + softmax + global s_sum  (2 vertices per iteration)
template <int L>
__device__ __forceinline__ void aw_body(
    float* sacc,
    const bf16* __restrict__ U, const int* __restrict__ anc, const int* __restrict__ leaf,
    const float* __restrict__ bl, const float* __restrict__ ap,
    float* __restrict__ s_out, int V, int blk, int nblk)
{
    const int tid  = threadIdx.x;
    const int lane = tid & 63;
    const int wid  = blk * 4 + (tid >> 6);
    const int nw   = nblk * 4;
    const float2 blv = *reinterpret_cast<const float2*>(bl + 2 * lane);
    const float2 apv = *reinterpret_cast<const float2*>(ap + 2 * lane);
    const unsigned int* Uw = reinterpret_cast<const unsigned int*>(U);
    float wacc[L];
#pragma unroll
    for (int l = 0; l < L; ++l) wacc[l] = 0.f;

    for (int vp = wid; vp < V / 2; vp += nw) {
        const int v0 = 2 * vp;
        int a0[L], f0[L], a1[L], f1[L];
        if (L == 4) {
            int4 ia = *reinterpret_cast<const int4*>(anc  + (size_t)v0 * 4);
            int4 ib = *reinterpret_cast<const int4*>(anc  + (size_t)v0 * 4 + 4);
            int4 fa = *reinterpret_cast<const int4*>(leaf + (size_t)v0 * 4);
            int4 fb = *reinterpret_cast<const int4*>(leaf + (size_t)v0 * 4 + 4);
            a0[0] = ia.x; a0[1] = ia.y; a0[2] = ia.z; a0[3] = ia.w;
            a1[0] = ib.x; a1[1] = ib.y; a1[2] = ib.z; a1[3] = ib.w;
            f0[0] = fa.x; f0[1] = fa.y; f0[2] = fa.z; f0[3] = fa.w;
            f1[0] = fb.x; f1[1] = fb.y; f1[2] = fb.z; f1[3] = fb.w;
        } else {
#pragma unroll
            for (int l = 0; l < L; ++l) {
                a0[l] = anc[(size_t)v0 * L + l];
                a1[l] = anc[(size_t)(v0 + 1) * L + l];
                f0[l] = leaf[(size_t)v0 * L + l];
                f1[l] = leaf[(size_t)(v0 + 1) * L + l];
            }
        }
        unsigned int ua0[L], ul0[L], ua1[L], ul1[L];
#pragma unroll
        for (int l = 0; l < L; ++l) {
            ua0[l] = Uw[(size_t)a0[l] * 128 + lane];
            ul0[l] = Uw[(size_t)f0[l] * 128 + 64 + lane];
            ua1[l] = Uw[(size_t)a1[l] * 128 + lane];
            ul1[l] = Uw[(size_t)f1[l] * 128 + 64 + lane];
        }
        float aw0[L], aw1[L];
#pragma unroll
        for (int l = 0; l < L; ++l) {
            float2 x0 = bf2x(ua0[l]), y0 = bf2x(ul0[l]);
            float2 x1 = bf2x(ua1[l]), y1 = bf2x(ul1[l]);
            float p0 = tanhf(x0.x + y0.x + blv.x) * apv.x + tanhf(x0.y + y0.y + blv.y) * apv.y;
            float p1 = tanhf(x1.x + y1.x + blv.x) * apv.x + tanhf(x1.y + y1.y + blv.y) * apv.y;
#pragma unroll
            for (int off = 32; off; off >>= 1) {
                p0 += __shfl_xor(p0, off, 64);
                p1 += __shfl_xor(p1, off, 64);
            }
            aw0[l] = p0; aw1[l] = p1;
        }
        float m0 = aw0[0], m1 = aw1[0];
#pragma unroll
        for (int l = 1; l < L; ++l) { m0 = fmaxf(m0, aw0[l]); m1 = fmaxf(m1, aw1[l]); }
        float d0 = 0.f, d1 = 0.f, e0[L], e1[L];
#pragma unroll
        for (int l = 0; l < L; ++l) {
            e0[l] = __expf(aw0[l] - m0); d0 += e0[l];
            e1[l] = __expf(aw1[l] - m1); d1 += e1[l];
        }
        float i0 = 1.f / d0, i1 = 1.f / d1;
#pragma unroll
        for (int l = 0; l < L; ++l) wacc[l] += e0[l] * i0 + e1[l] * i1;
    }
    if (lane == 0) {
#pragma unroll
        for (int l = 0; l < L; ++l) atomicAdd(&sacc[l], wacc[l]);
    }
    __syncthreads();
    if (tid < L) atomicAdd(&s_out[tid], sacc[tid]);
}

__global__ __launch_bounds__(256) void aw_all(
    const bf16* __restrict__ U_d, const int* __restrict__ anc_d, const int* __restrict__ leaf_d,
    const float* __restrict__ bl_d, const float* __restrict__ ap_d,
    const bf16* __restrict__ U_p, const int* __restrict__ anc_p, const int* __restrict__ leaf_p,
    const float* __restrict__ bl_p, const float* __restrict__ ap_p,
    const bf16* __restrict__ U_a, const int* __restrict__ anc_a, const int* __restrict__ leaf_a,
    const float* __restrict__ bl_a, const float* __restrict__ ap_a,
    float* __restrict__ s_sum)
{
    __shared__ float sacc[5];
    const int tid = threadIdx.x;
    if (tid < 5) sacc[tid] = 0.f;
    __syncthreads();
    int bx = blockIdx.x;
    if (bx < 512)      aw_body<4>(sacc, U_d, anc_d, leaf_d, bl_d, ap_d, s_sum + 0, VD, bx, 512);
    else if (bx < 768) aw_body<4>(sacc, U_p, anc_p, leaf_p, bl_p, ap_p, s_sum + 4, VP, bx - 512, 256);
    else               aw_body<5>(sacc, U_a, anc_a, leaf_a, bl_a, ap_a, s_sum + 8, VA, bx - 768, 256);
}

// ---------------- K3: all_emb (float4 gathers, 2 vertices per iteration)
template <int L>
__device__ __forceinline__ void allemb_body(
    const float* __restrict__ emb, const int* __restrict__ anc,
    const float* __restrict__ s, float* __restrict__ out, int V, int blk, int nblk)
{
    const int tid   = threadIdx.x;
    const int lane4 = tid & 31;
    const int vslot = tid >> 5;
    const float4* emb4 = reinterpret_cast<const float4*>(emb);
    float4* out4 = reinterpret_cast<float4*>(out);
    float sv[L];
#pragma unroll
    for (int l = 0; l < L; ++l) sv[l] = s[l];
    for (int vp = blk * 8 + vslot; vp < V / 2; vp += nblk * 8) {
        const int v0 = 2 * vp;
        int a0[L], a1[L];
        if (L == 4) {
            int4 ia = *reinterpret_cast<const int4*>(anc + (size_t)v0 * 4);
            int4 ib = *reinterpret_cast<const int4*>(anc + (size_t)v0 * 4 + 4);
            a0[0] = ia.x; a0[1] = ia.y; a0[2] = ia.z; a0[3] = ia.w;
            a1[0] = ib.x; a1[1] = ib.y; a1[2] = ib.z; a1[3] = ib.w;
        } else {
#pragma unroll
            for (int l = 0; l < L; ++l) {
                a0[l] = anc[(size_t)v0 * L + l];
                a1[l] = anc[(size_t)(v0 + 1) * L + l];
            }
        }
        float4 e0[L], e1[L];
#pragma unroll
        for (int l = 0; l < L; ++l) {
            e0[l] = emb4[(size_t)a0[l] * 32 + lane4];
            e1[l] = emb4[(size_t)a1[l] * 32 + lane4];
        }
        float4 r0 = make_float4(0.f, 0.f, 0.f, 0.f);
        float4 r1 = make_float4(0.f, 0.f, 0.f, 0.f);
#pragma unroll
        for (int l = 0; l < L; ++l) {
            r0.x += sv[l] * e0[l].x; r0.y += sv[l] * e0[l].y;
            r0.z += sv[l] * e0[l].z; r0.w += sv[l] * e0[l].w;
            r1.x += sv[l] * e1[l].x; r1.y += sv[l] * e1[l].y;
            r1.z += sv[l] * e1[l].z; r1.w += sv[l] * e1[l].w;
        }
        out4[(size_t)v0 * 32 + lane4]       = r0;
        out4[(size_t)(v0 + 1) * 32 + lane4] = r1;
    }
}

__global__ __launch_bounds__(256) void allemb_all(
    const float* __restrict__ emb_d, const int* __restrict__ anc_d,
    const float* __restrict__ emb_p, const int* __restrict__ anc_p,
    const float* __restrict__ emb_a, const int* __restrict__ anc_a,
    const float* __restrict__ s_sum, float* __restrict__ all_emb)
{
    int bx = blockIdx.x;
    if (bx < 512)
        allemb_body<4>(emb_d, anc_d, s_sum + 0, all_emb, VD, bx, 512);
    else if (bx < 768)
        allemb_body<4>(emb_p, anc_p, s_sum + 4, all_emb + (size_t)VD * HID, VP, bx - 512, 256);
    else
        allemb_body<5>(emb_a, anc_a, s_sum + 8, all_emb + (size_t)(VD + VP) * HID, VA, bx - 768, 256);
}

// ---------------- K4: segment sum — max-MLP (R7/R10 proven best)
__global__ __launch_bounds__(256) void segsum_mlp(
    const float* __restrict__ all_emb,
    const int* __restrict__ lx, const int* __restrict__ segL, float* __restrict__ le,
    const int* __restrict__ rx, const int* __restrict__ segR, float* __restrict__ re)
{
    __shared__ float4 red[4][32];
    const int tid  = threadIdx.x;
    const int b    = blockIdx.x & (BB - 1);
    const int lane = tid & 63;
    const int w    = tid >> 6;
    const int* x;
    const int* seg;
    float* out;
    if (blockIdx.x < BB) { x = lx; seg = segL; out = le; }
    else                 { x = rx; seg = segR; out = re; }
    const int lo = seg[b], hi = seg[b + 1];
    const int half  = lane >> 5;
    const int lane4 = lane & 31;
    const float4* AE4 = reinterpret_cast<const float4*>(all_emb);
    float4 acc = make_float4(0.f, 0.f, 0.f, 0.f);

    for (int tb = lo + 16 * w; tb < hi; tb += 64) {
        int idxv = x[min(tb + (lane & 15), hi - 1)];
        float4 v[8];
        int val[8];
#pragma unroll
        for (int u = 0; u < 8; ++u) {
            int src = 2 * u + half;
            int ridx = __shfl(idxv, src, 64);
            val[u] = (tb + src) < hi;
            v[u] = AE4[(size_t)ridx * 32 + lane4];
        }
#pragma unroll
        for (int u = 0; u < 8; ++u) {
            if (val[u]) {
                acc.x += v[u].x; acc.y += v[u].y;
                acc.z += v[u].z; acc.w += v[u].w;
            }
        }
    }
    acc.x += __shfl_xor(acc.x, 32, 64);
    acc.y += __shfl_xor(acc.y, 32, 64);
    acc.z += __shfl_xor(acc.z, 32, 64);
    acc.w += __shfl_xor(acc.w, 32, 64);
    if (lane < 32) red[w][lane4] = acc;
    __syncthreads();
    if (tid < 32) {
        float4 r0 = red[0][tid], r1 = red[1][tid], r2 = red[2][tid], r3 = red[3][tid];
        float4 s;
        s.x = r0.x + r1.x + r2.x + r3.x;
        s.y = r0.y + r1.y + r2.y + r3.y;
        s.z = r0.z + r1.z + r2.z + r3.z;
        s.w = r0.w + r1.w + r2.w + r3.w;
        reinterpret_cast<float4*>(out)[(size_t)b * 32 + tid] = s;
    }
}

// ---------------- K5a: NTN bilinear via split-bf16 MFMA (6 cross-products ≈ f32).
__global__ __launch_bounds__(256) void ntn_mfma(
    const float* __restrict__ le, const float* __restrict__ re,
    const bf16* __restrict__ W3h, const bf16* __restrict__ W3m, const bf16* __restrict__ W3l,
    float* __restrict__ part)
{
    __shared__ float Rlds[64][17];
    const int tid  = threadIdx.x;
    const int bg   = blockIdx.x;     // 0..63
    const int ch   = blockIdx.y;     // 0..7
    const int w    = tid >> 6;
    const int lane = tid & 63;
    const int m    = lane & 15;
    const int quad = lane >> 4;
    const int rb   = bg * 64 + w * 16 + m;

    for (int idx = tid; idx < 1024; idx += 256) {
        int row = idx >> 4, jl = idx & 15;
        Rlds[row][jl] = re[(size_t)(bg * 64 + row) * HID + ch * 16 + jl];
    }

    bf16x8 lh[4], lm[4], ll[4];
    {
        const float* lp = le + (size_t)rb * HID + quad * 8;
#pragma unroll
        for (int q = 0; q < 4; ++q) {
            float4 f0 = *reinterpret_cast<const float4*>(lp + 32 * q);
            float4 f1 = *reinterpret_cast<const float4*>(lp + 32 * q + 4);
            float x[8] = {f0.x, f0.y, f0.z, f0.w, f1.x, f1.y, f1.z, f1.w};
            FragU fh, fm, fl;
#pragma unroll
            for (int j = 0; j < 8; ++j) {
                bf16 h = __float2bfloat16(x[j]);
                float r = x[j] - __bfloat162float(h);
                bf16 md = __float2bfloat16(r);
                float r2 = r - __bfloat162float(md);
                fh.s[j] = *reinterpret_cast<short*>(&h);
                fm.s[j] = *reinterpret_cast<short*>(&md);
                fl.s[j] = bfs(r2);
            }
            lh[q] = fh.v; lm[q] = fm.v; ll[q] = fl.v;
        }
    }
    __syncthreads();

    const bf16x8* Whf = reinterpret_cast<const bf16x8*>(W3h);
    const bf16x8* Wmf = reinterpret_cast<const bf16x8*>(W3m);
    const bf16x8* Wlf = reinterpret_cast<const bf16x8*>(W3l);

    float blin[4] = {0.f, 0.f, 0.f, 0.f};
#pragma unroll 2
    for (int tl = 0; tl < 16; ++tl) {
        const int t = ch * 16 + tl;
        f32x4 acc = (f32x4){0.f, 0.f, 0.f, 0.f};
#pragma unroll
        for (int q = 0; q < 4; ++q) {
            const int fi = (t * 4 + q) * 64 + lane;
            bf16x8 wh = Whf[fi], wm = Wmf[fi], wl = Wlf[fi];
            acc = __builtin_amdgcn_mfma_f32_16x16x32_bf16(wh, lh[q], acc, 0, 0, 0);
            acc = __builtin_amdgcn_mfma_f32_16x16x32_bf16(wh, lm[q], acc, 0, 0, 0);
            acc = __builtin_amdgcn_mfma_f32_16x16x32_bf16(wm, lh[q], acc, 0, 0, 0);
            acc = __builtin_amdgcn_mfma_f32_16x16x32_bf16(wh, ll[q], acc, 0, 0, 0);
            acc = __builtin_amdgcn_mfma_f32_16x16x32_bf16(wl, lh[q], acc, 0, 0, 0);
            acc = __builtin_amdgcn_mfma_f32_16x16x32_bf16(wm, lm[q], acc, 0, 0, 0);
        }
        float rt = Rlds[w * 16 + m][tl];
        blin[0] += acc.x * rt;
        blin[1] += acc.y * rt;
        blin[2] += acc.z * rt;
        blin[3] += acc.w * rt;
    }

    size_t base = ((size_t)ch * BB + rb) * PD + quad * 4;
    *reinterpret_cast<float4*>(&part[base]) = make_float4(blin[0], blin[1], blin[2], blin[3]);
}

// ---------------- K5b: sum partials + block term + tanh + fc + sigmoid
__global__ __launch_bounds__(256) void ntn_epi(
    const float* __restrict__ part, const float* __restrict__ le, const float* __restrict__ re,
    const float* __restrict__ Vntn, const float* __restrict__ bntn,
    const float* __restrict__ wfc, const float* __restrict__ bfc,
    float* __restrict__ out)
{
    __shared__ float Vlds[16 * 257];
    __shared__ float LE[16 * 128];
    __shared__ float RE[16 * 128];
    const int tid = threadIdx.x;
    const int b0  = blockIdx.x * 16;
    for (int i = tid; i < 4096; i += 256) Vlds[(i >> 8) * 257 + (i & 255)] = Vntn[i];
    for (int i = tid; i < 2048; i += 256) {
        LE[i] = le[(size_t)b0 * HID + i];
        RE[i] = re[(size_t)b0 * HID + i];
    }
    __syncthreads();
    const int bl = tid >> 4, p = tid & 15;
    const int b  = b0 + bl;
    float bil = 0.f;
#pragma unroll
    for (int by = 0; by < 8; ++by) bil += part[((size_t)by * BB + b) * PD + p];
    float s = bil + bntn[p];
    const float* Vp   = &Vlds[p * 257];
    const float* lrow = &LE[bl * 128];
    const float* rrow = &RE[bl * 128];
#pragma unroll 8
    for (int c = 0; c < 128; ++c) s += lrow[c] * Vp[c] + rrow[c] * Vp[128 + c];
    float x = tanhf(s) * wfc[p];
    x += __shfl_xor(x, 1, 64);
    x += __shfl_xor(x, 2, 64);
    x += __shfl_xor(x, 4, 64);
    x += __shfl_xor(x, 8, 64);
    if (p == 0) out[b] = 1.f / (1.f + __expf(-(x + bfc[0])));
}

extern "C" void kernel_launch(void* const* d_in, const int* in_sizes, int n_in,
                              void* d_out, int out_size, void* d_ws, size_t ws_size,
                              hipStream_t stream)
{
    const int* left_x      = (const int*)d_in[0];
    const int* right_x     = (const int*)d_in[2];
    const int* left_batch  = (const int*)d_in[4];
    const int* right_batch = (const int*)d_in[5];
    const int* anc_d  = (const int*)d_in[8];
    const int* leaf_d = (const int*)d_in[9];
    const int* anc_p  = (const int*)d_in[10];
    const int* leaf_p = (const int*)d_in[11];
    const int* anc_a  = (const int*)d_in[12];
    const int* leaf_a = (const int*)d_in[13];
    const float* emb_d = (const float*)d_in[14];
    const float* emb_p = (const float*)d_in[15];
    const float* emb_a = (const float*)d_in[16];
    const float* Wl_d = (const float*)d_in[17];
    const float* bl_d = (const float*)d_in[18];
    const float* ap_d = (const float*)d_in[19];
    const float* Wl_p = (const float*)d_in[20];
    const float* bl_p = (const float*)d_in[21];
    const float* ap_p = (const float*)d_in[22];
    const float* Wl_a = (const float*)d_in[23];
    const float* bl_a = (const float*)d_in[24];
    const float* ap_a = (const float*)d_in[25];
    const float* W_ntn = (const float*)d_in[26];
    const float* V_ntn = (const float*)d_in[27];
    const float* b_ntn = (const float*)d_in[28];
    const float* w_fc  = (const float*)d_in[29];
    const float* b_fc  = (const float*)d_in[30];
    float* out = (float*)d_out;

    float* ws = (float*)d_ws;
    float* s_sum   = ws;                                    // 64 floats (16 used)
    float* le      = ws + 64;                               // 4096*128
    float* re      = le + (size_t)BB * HID;                 // 4096*128
    float* all_emb = re + (size_t)BB * HID;                 // 18000*128
    float* part    = all_emb + (size_t)(VD + VP + VA) * HID;// 8*4096*16
    int*   segL    = (int*)(part + (size_t)8 * BB * PD);    // 4100
    int*   segR    = segL + 4100;                           // 4100
    bf16*  U       = (bf16*)(segR + 4100);                  // 23400*256 bf16
    bf16*  U_d = U;
    bf16*  U_p = U_d + (size_t)NGD * 256;
    bf16*  U_a = U_p + (size_t)NGP * 256;
    bf16*  B3_d = U_a + (size_t)NGA * 256;                  // 3 * 32768 bf16
    bf16*  B3_p = B3_d + 32768;
    bf16*  B3_a = B3_p + 32768;
    bf16*  W3h  = B3_a + 32768;                             // 3 * 262144 bf16
    bf16*  W3m  = W3h + 262144;
    bf16*  W3l  = W3m + 262144;

    prologue<<<209, 256, 0, stream>>>(
        Wl_d, Wl_p, Wl_a, B3_d, B3_p, B3_a,
        left_batch, right_batch, segL, segR, s_sum,
        W_ntn, W3h, W3m, W3l);

    stage1_mfma<<<NB_D + NB_P + NB_A, 256, 0, stream>>>(
        emb_d, B3_d, U_d, emb_p, B3_p, U_p, emb_a, B3_a, U_a);

    aw_all<<<1024, 256, 0, stream>>>(
        U_d, anc_d, leaf_d, bl_d, ap_d,
        U_p, anc_p, leaf_p, bl_p, ap_p,
        U_a, anc_a, leaf_a, bl_a, ap_a, s_sum);

    allemb_all<<<1024, 256, 0, stream>>>(
        emb_d, anc_d, emb_p, anc_p, emb_a, anc_a, s_sum, all_emb);

    segsum_mlp<<<2 * BB, 256, 0, stream>>>(
        all_emb, left_x, segL, le, right_x, segR, re);

    ntn_mfma<<<dim3(64, 8), 256, 0, stream>>>(le, re, W3h, W3m, W3l, part);

    ntn_epi<<<BB / 16, 256, 0, stream>>>(part, le, re, V_ntn, b_ntn, w_fc, b_fc, out);
}